// Round 3
// baseline (349.224 us; speedup 1.0000x reference)
//
#include <hip/hip_runtime.h>
#include <math.h>

#define B_ 4
#define N_ 2048
#define C_ 64
#define K_ 32
#define BN_ (B_ * N_)  // 8192

// ws float layout (every region fully written each launch before it is read):
// [0, 4)           ACCUM: [0]=nll_sum (atomic), zeroed by k_prep
// [64, 8256)       SUMS   B*K*C   (written wholesale by k_cluster)
// [8256, 8384)     COUNTS B*K     (written wholesale by k_cluster)
// [8448, 16640)    SX (BN)        (written by k_prep)
// [16640, 24832)   SY (BN)        (written by k_prep)
// [24832, 28928)   APART (2048 blocks * {sum, cnt})
#define WS_ACCUM 0
#define WS_SUMS 64
#define WS_COUNTS 8256
#define WS_SX 8448
#define WS_SY 16640
#define WS_APART 24832

// Zero accum + s = embedding + abs_coords (SoA).
__global__ __launch_bounds__(256) void k_prep(
    const float* __restrict__ emb, const float* __restrict__ absc,
    float* __restrict__ ws) {
  int i = blockIdx.x * 256 + threadIdx.x;
  if (i < 4) ws[WS_ACCUM + i] = 0.0f;
  if (i < BN_) {
    const float2* e2 = (const float2*)emb;
    const float2* a2 = (const float2*)absc;
    float2 ev = e2[i], av = a2[i];
    ws[WS_SX + i] = ev.x + av.x;
    ws[WS_SY + i] = ev.y + av.y;
  }
}

// 4 blocks (one per batch) x 1024 threads (16 waves). lane = channel, wave
// strides rows. Normalize per row via shuffle reduce, LDS-atomic cluster
// sums/counts, then bulk-write SUMS/COUNTS (no global atomics, no k_means —
// the divide is folded into k_logits' register load).
__global__ __launch_bounds__(1024) void k_cluster(
    const float* __restrict__ contr, const int* __restrict__ labels,
    float* __restrict__ ws) {
  __shared__ float ls[K_ * C_ + K_];
  int t = threadIdx.x, lane = t & 63, w = t >> 6;
  int b = blockIdx.x;
  for (int i = t; i < K_ * C_ + K_; i += 1024) ls[i] = 0.0f;
  __syncthreads();
  for (int r = w; r < N_; r += 16) {
    int row = b * N_ + r;
    float x = contr[row * C_ + lane];
    float ss = x * x;
#pragma unroll
    for (int off = 32; off > 0; off >>= 1) ss += __shfl_xor(ss, off);
    float inv = 1.0f / fmaxf(sqrtf(ss), 1e-12f);
    int lbl = labels[row];
    atomicAdd(&ls[lbl * C_ + lane], x * inv);
    if (lane == 0) atomicAdd(&ls[K_ * C_ + lbl], 1.0f);
  }
  __syncthreads();
  for (int i = t; i < K_ * C_; i += 1024) ws[WS_SUMS + b * K_ * C_ + i] = ls[i];
  if (t < K_) ws[WS_COUNTS + b * K_ + t] = ls[K_ * C_ + t];
}

// 512 blocks x 128 threads (2 waves). Block = 16 rows. lane = column:
// wave w covers cols [w*64, w*64+64) of the B*K=128 logit columns.
// Means (with count divide) live in 64 VGPRs per lane; rows stream through
// LDS as wave-uniform b128 broadcasts -> 1 ds_read : 4 v_fma.
__global__ __launch_bounds__(128) void k_logits_nll(
    const float* __restrict__ contr, const int* __restrict__ labels,
    float* __restrict__ ws) {
  __shared__ float lc[16 * C_];      // raw contr rows
  __shared__ float invr[16];
  __shared__ float lm[2][16], lsv[2][16], ltl[16];
  int t = threadIdx.x, lane = t & 63, w = t >> 6;
  int r0 = blockIdx.x * 16;
  int j = w * 64 + lane;  // my logit column
  // means column j -> registers, divide fused
  float invc = 1.0f / fmaxf(ws[WS_COUNTS + j], 1.0f);
  float4 mk[16];
  const float4* sums4 = (const float4*)(ws + WS_SUMS);
#pragma unroll
  for (int q = 0; q < 16; ++q) {
    float4 v = sums4[j * 16 + q];
    mk[q] = make_float4(v.x * invc, v.y * invc, v.z * invc, v.w * invc);
  }
  // stage 16 rows of contr
  const float4* c4 = (const float4*)(contr + r0 * C_);
  float4* lc4 = (float4*)lc;
  lc4[t] = c4[t];
  lc4[t + 128] = c4[t + 128];
  __syncthreads();
  // per-row inverse norms
  for (int r = w; r < 16; r += 2) {
    float x = lc[r * C_ + lane];
    float ss = x * x;
#pragma unroll
    for (int off = 32; off > 0; off >>= 1) ss += __shfl_xor(ss, off);
    if (lane == 0) invr[r] = 1.0f / fmaxf(sqrtf(ss), 1e-12f);
  }
  __syncthreads();
  for (int r = 0; r < 16; ++r) {
    const float4* cr = lc4 + r * 16;
    float acc = 0.0f;
#pragma unroll
    for (int q = 0; q < 16; ++q) {
      float4 cv = cr[q];
      acc += cv.x * mk[q].x + cv.y * mk[q].y + cv.z * mk[q].z + cv.w * mk[q].w;
    }
    acc *= invr[r];  // (c*inv)·mean == inv*(c·mean)
    int tgt = labels[r0 + r];  // [0,32): lives in wave 0's columns
    float m = acc;
#pragma unroll
    for (int off = 32; off > 0; off >>= 1) m = fmaxf(m, __shfl_xor(m, off));
    float e = __expf(acc - m), s = e;
#pragma unroll
    for (int off = 32; off > 0; off >>= 1) s += __shfl_xor(s, off);
    float tl = __shfl(acc, tgt);
    if (lane == 0) {
      lm[w][r] = m;
      lsv[w][r] = s;
      if (w == 0) ltl[r] = tl;
    }
  }
  __syncthreads();
  if (t < 16) {
    float m0 = lm[0][t], m1 = lm[1][t];
    float mm = fmaxf(m0, m1);
    float ss = lsv[0][t] * __expf(m0 - mm) + lsv[1][t] * __expf(m1 - mm);
    float nll = (mm + __logf(ss)) - ltl[t];
#pragma unroll
    for (int off = 8; off > 0; off >>= 1) nll += __shfl_xor(nll, off);
    if (t == 0) atomicAdd(&ws[WS_ACCUM + 0], nll);
  }
}

__device__ __forceinline__ void pair4(float sx, float sy, float4 xs, float4 ys,
                                      int4 m, float& acc, int& cnt) {
  float dx, dy, d2, v;
  dx = sx - xs.x; dy = sy - ys.x; d2 = dx * dx + dy * dy;
  v = 1.0f - __expf(d2 * -0.1f);
  if (m.x == 1) { acc += v; cnt += 1; }
  dx = sx - xs.y; dy = sy - ys.y; d2 = dx * dx + dy * dy;
  v = 1.0f - __expf(d2 * -0.1f);
  if (m.y == 1) { acc += v; cnt += 1; }
  dx = sx - xs.z; dy = sy - ys.z; d2 = dx * dx + dy * dy;
  v = 1.0f - __expf(d2 * -0.1f);
  if (m.z == 1) { acc += v; cnt += 1; }
  dx = sx - xs.w; dy = sy - ys.w; d2 = dx * dx + dy * dy;
  v = 1.0f - __expf(d2 * -0.1f);
  if (m.w == 1) { acc += v; cnt += 1; }
}

// 2048 blocks x 256. Block = (batch b, column half h, 8-row chunk).
// Thread owns 4 columns (loop-invariant xs/ys float4, loaded ONCE) and
// iterates 8 rows: 8 named int4 buffers -> 8 mask loads provably in flight;
// row s-values are wave-uniform scalars. No atomic tail: per-block partial.
__global__ __launch_bounds__(256) void k_anchor(
    const int* __restrict__ mask, float* __restrict__ ws) {
  __shared__ float red[8];
  int t = threadIdx.x;
  int g = blockIdx.x;
  int b = g >> 9;              // 512 blocks per batch
  int h = (g >> 8) & 1;        // column half
  int rowbase = (g & 255) * 8;
  int col0 = h * 1024;
  const float* sxp = ws + WS_SX + b * N_;
  const float* syp = ws + WS_SY + b * N_;
  float4 xs = *(const float4*)(sxp + col0 + t * 4);
  float4 ys = *(const float4*)(syp + col0 + t * 4);
  float s0x = sxp[rowbase + 0], s0y = syp[rowbase + 0];
  float s1x = sxp[rowbase + 1], s1y = syp[rowbase + 1];
  float s2x = sxp[rowbase + 2], s2y = syp[rowbase + 2];
  float s3x = sxp[rowbase + 3], s3y = syp[rowbase + 3];
  float s4x = sxp[rowbase + 4], s4y = syp[rowbase + 4];
  float s5x = sxp[rowbase + 5], s5y = syp[rowbase + 5];
  float s6x = sxp[rowbase + 6], s6y = syp[rowbase + 6];
  float s7x = sxp[rowbase + 7], s7y = syp[rowbase + 7];
  const int4* mp = (const int4*)(mask + (size_t)(b * N_ + rowbase) * N_ + col0) + t;
  int4 m0 = mp[0 * 512], m1 = mp[1 * 512], m2 = mp[2 * 512], m3 = mp[3 * 512];
  int4 m4 = mp[4 * 512], m5 = mp[5 * 512], m6 = mp[6 * 512], m7 = mp[7 * 512];
  float acc = 0.0f;
  int cnt = 0;
  pair4(s0x, s0y, xs, ys, m0, acc, cnt);
  pair4(s1x, s1y, xs, ys, m1, acc, cnt);
  pair4(s2x, s2y, xs, ys, m2, acc, cnt);
  pair4(s3x, s3y, xs, ys, m3, acc, cnt);
  pair4(s4x, s4y, xs, ys, m4, acc, cnt);
  pair4(s5x, s5y, xs, ys, m5, acc, cnt);
  pair4(s6x, s6y, xs, ys, m6, acc, cnt);
  pair4(s7x, s7y, xs, ys, m7, acc, cnt);
  float cntf = (float)cnt;
#pragma unroll
  for (int off = 32; off > 0; off >>= 1) {
    acc += __shfl_xor(acc, off);
    cntf += __shfl_xor(cntf, off);
  }
  int w = t >> 6;
  if ((t & 63) == 0) { red[w * 2] = acc; red[w * 2 + 1] = cntf; }
  __syncthreads();
  if (t == 0) {
    ws[WS_APART + g * 2 + 0] = red[0] + red[2] + red[4] + red[6];
    ws[WS_APART + g * 2 + 1] = red[1] + red[3] + red[5] + red[7];
  }
}

// Single block: reduce 2048 anchor partials + combine with nll.
__global__ __launch_bounds__(256) void k_final(
    const float* __restrict__ ws, float* __restrict__ out) {
  __shared__ float red[8];
  int t = threadIdx.x;
  float a = 0.0f, c = 0.0f;
  for (int i = t; i < 2048; i += 256) {
    a += ws[WS_APART + i * 2 + 0];
    c += ws[WS_APART + i * 2 + 1];
  }
#pragma unroll
  for (int off = 32; off > 0; off >>= 1) {
    a += __shfl_xor(a, off);
    c += __shfl_xor(c, off);
  }
  int w = t >> 6;
  if ((t & 63) == 0) { red[w * 2] = a; red[w * 2 + 1] = c; }
  __syncthreads();
  if (t == 0) {
    float at = red[0] + red[2] + red[4] + red[6];
    float ct = red[1] + red[3] + red[5] + red[7];
    out[0] = at / ct + 10.0f * ws[WS_ACCUM + 0] * (1.0f / (float)BN_);
  }
}

extern "C" void kernel_launch(void* const* d_in, const int* in_sizes, int n_in,
                              void* d_out, int out_size, void* d_ws, size_t ws_size,
                              hipStream_t stream) {
  const float* emb    = (const float*)d_in[0];
  const float* contr  = (const float*)d_in[1];
  const float* absc   = (const float*)d_in[2];
  const int*   mask   = (const int*)d_in[3];
  const int*   labels = (const int*)d_in[4];
  float* ws  = (float*)d_ws;
  float* out = (float*)d_out;

  k_prep<<<33, 256, 0, stream>>>(emb, absc, ws);
  k_cluster<<<B_, 1024, 0, stream>>>(contr, labels, ws);
  k_logits_nll<<<BN_ / 16, 128, 0, stream>>>(contr, labels, ws);
  k_anchor<<<2048, 256, 0, stream>>>(mask, ws);
  k_final<<<1, 256, 0, stream>>>(ws, out);
}

// Round 4
// 146.304 us; speedup vs baseline: 2.3870x; 2.3870x over previous
//
#include <hip/hip_runtime.h>
#include <math.h>

#define B_ 4
#define N_ 2048
#define C_ 64
#define K_ 32
#define BN_ (B_ * N_)  // 8192

// ws float layout (all regions fully written each launch before read):
// [0]              nll accumulator (zeroed by k_prep, atomicAdd by k_logits)
// [64, 8256)       INVN  per-row 1/||contr_row||  (k_prep)
// [8320, 16512)    SX = emb.x + absc.x  (k_prep)
// [16512, 24704)   SY = emb.y + absc.y  (k_prep)
// [24704, 32896)   MEANS B*K*C, count-divide fused (k_cluster)
// [32896, 36992)   APART 2048 * {sum, cnt} (k_anchor)
#define WS_NLL 0
#define WS_INVN 64
#define WS_SX 8320
#define WS_SY 16512
#define WS_MEANS 24704
#define WS_APART 32896

typedef const __attribute__((address_space(1))) void* gas_ptr;
typedef __attribute__((address_space(3))) void* las_ptr;

// 2048 blocks x 256: wave = one contr row (inv-norm); first 8192 flat threads
// also write SX/SY; thread 0 zeroes the nll accumulator.
__global__ __launch_bounds__(256) void k_prep(
    const float* __restrict__ emb, const float* __restrict__ absc,
    const float* __restrict__ contr, float* __restrict__ ws) {
  int t = threadIdx.x, lane = t & 63, w = t >> 6;
  int flat = blockIdx.x * 256 + t;
  if (flat == 0) ws[WS_NLL] = 0.0f;
  if (flat < BN_) {
    float2 ev = ((const float2*)emb)[flat];
    float2 av = ((const float2*)absc)[flat];
    ws[WS_SX + flat] = ev.x + av.x;
    ws[WS_SY + flat] = ev.y + av.y;
  }
  int row = blockIdx.x * 4 + w;
  float x = contr[row * C_ + lane];
  float ss = x * x;
#pragma unroll
  for (int off = 32; off > 0; off >>= 1) ss += __shfl_xor(ss, off);
  if (lane == 0) ws[WS_INVN + row] = 1.0f / fmaxf(sqrtf(ss), 1e-12f);
}

// 128 blocks (one per (batch, cluster)) x 256. Labels staged to LDS once;
// each wave ballot-scans 512 rows (8 ballots, not 512 serial reads); matched
// rows pulled as coalesced 256B wave-loads. Divide fused -> MEANS directly.
__global__ __launch_bounds__(256) void k_cluster(
    const float* __restrict__ contr, const int* __restrict__ labels,
    float* __restrict__ ws) {
  __shared__ int lsLab[N_];        // 8 KB
  __shared__ float lsum[4][64];
  __shared__ float lcnt[4];
  int t = threadIdx.x, lane = t & 63, w = t >> 6;
  int b = blockIdx.x >> 5, k = blockIdx.x & 31;
  const int4* lab4 = (const int4*)(labels + b * N_);
  int4* l4 = (int4*)lsLab;
  l4[t] = lab4[t];
  l4[t + 256] = lab4[t + 256];
  __syncthreads();
  float acc = 0.0f, cnt = 0.0f;
  for (int g0 = w * 512; g0 < w * 512 + 512; g0 += 64) {
    unsigned long long mb = __ballot(lsLab[g0 + lane] == k);
    while (mb) {
      int bit = __ffsll((unsigned long long)mb) - 1;
      mb &= mb - 1;
      int r = b * N_ + g0 + bit;
      float inv = ws[WS_INVN + r];
      acc += contr[(size_t)r * C_ + lane] * inv;
      cnt += 1.0f;
    }
  }
  lsum[w][lane] = acc;
  if (lane == 0) lcnt[w] = cnt;
  __syncthreads();
  if (t < 64) {
    float s = lsum[0][t] + lsum[1][t] + lsum[2][t] + lsum[3][t];
    float c = lcnt[0] + lcnt[1] + lcnt[2] + lcnt[3];
    ws[WS_MEANS + (b * K_ + k) * C_ + t] = s / fmaxf(c, 1.0f);
  }
}

// 256 blocks x 128 (2 waves). Block = 32 rows. lane = logit column
// (wave w -> cols [w*64, w*64+64)). Means held in 16 float4 VGPRs; rows
// stream via LDS wave-uniform b128 broadcasts. Softmax + nll fused.
__global__ __launch_bounds__(128) void k_logits_nll(
    const float* __restrict__ contr, const int* __restrict__ labels,
    float* __restrict__ ws) {
  __shared__ float lc[32 * C_];    // 8 KB raw rows
  __shared__ float lm[2][32], lsv[2][32], ltl[32];
  int t = threadIdx.x, lane = t & 63, w = t >> 6;
  int r0 = blockIdx.x * 32;
  int j = w * 64 + lane;
  const float4* mean4 = (const float4*)(ws + WS_MEANS);
  float4 mk[16];
#pragma unroll
  for (int q = 0; q < 16; ++q) mk[q] = mean4[j * 16 + q];
  const float4* c4 = (const float4*)(contr + (size_t)r0 * C_);
  float4* lc4 = (float4*)lc;
  lc4[t] = c4[t];
  lc4[t + 128] = c4[t + 128];
  lc4[t + 256] = c4[t + 256];
  lc4[t + 384] = c4[t + 384];
  __syncthreads();
  for (int r = 0; r < 32; ++r) {
    const float4* cr = lc4 + r * 16;
    float acc = 0.0f;
#pragma unroll
    for (int q = 0; q < 16; ++q) {
      float4 cv = cr[q];
      acc += cv.x * mk[q].x + cv.y * mk[q].y + cv.z * mk[q].z + cv.w * mk[q].w;
    }
    acc *= ws[WS_INVN + r0 + r];
    float m = acc;
#pragma unroll
    for (int off = 32; off > 0; off >>= 1) m = fmaxf(m, __shfl_xor(m, off));
    float s = __expf(acc - m);
#pragma unroll
    for (int off = 32; off > 0; off >>= 1) s += __shfl_xor(s, off);
    int tgt = labels[r0 + r];            // [0,32): wave 0's columns
    float tl = __shfl(acc, tgt);
    if (lane == 0) {
      lm[w][r] = m;
      lsv[w][r] = s;
      if (w == 0) ltl[r] = tl;
    }
  }
  __syncthreads();
  if (t < 32) {
    float m0 = lm[0][t], m1 = lm[1][t];
    float mm = fmaxf(m0, m1);
    float ss = lsv[0][t] * __expf(m0 - mm) + lsv[1][t] * __expf(m1 - mm);
    float nll = (mm + __logf(ss)) - ltl[t];
#pragma unroll
    for (int off = 16; off > 0; off >>= 1) nll += __shfl_xor(nll, off);
    if (t == 0) atomicAdd(&ws[WS_NLL], nll);
  }
}

__device__ __forceinline__ void pair4(float sx, float sy, float4 xs, float4 ys,
                                      int4 m, float& acc, int& cnt) {
  float dx, dy, d2, v;
  dx = sx - xs.x; dy = sy - ys.x; d2 = dx * dx + dy * dy;
  v = 1.0f - __expf(d2 * -0.1f);
  if (m.x == 1) { acc += v; cnt += 1; }
  dx = sx - xs.y; dy = sy - ys.y; d2 = dx * dx + dy * dy;
  v = 1.0f - __expf(d2 * -0.1f);
  if (m.y == 1) { acc += v; cnt += 1; }
  dx = sx - xs.z; dy = sy - ys.z; d2 = dx * dx + dy * dy;
  v = 1.0f - __expf(d2 * -0.1f);
  if (m.z == 1) { acc += v; cnt += 1; }
  dx = sx - xs.w; dy = sy - ys.w; d2 = dx * dx + dy * dy;
  v = 1.0f - __expf(d2 * -0.1f);
  if (m.w == 1) { acc += v; cnt += 1; }
}

// 2048 blocks x 256. Block = 4 mask rows (32 KB contiguous). Each wave issues
// 8 async 1KB global->LDS loads (global_load_lds width=16: no dest VGPRs, so
// the compiler CANNOT sink/serialize them — R2's VGPR=24 showed plain loads
// get sunk), one s_waitcnt vmcnt(0), then processes from LDS with
// register-resident coordinates. Chunk mapping c = i*256 + t gives each
// thread only TWO column positions (t, t+256) -> xs/ys loaded once, and
// row r = i>>1 -> wave-uniform scalars. No barrier: waves read only their
// own staged chunks. Per-block partials (no global atomics).
__global__ __launch_bounds__(256) void k_anchor(
    const int* __restrict__ mask, float* __restrict__ ws) {
  __shared__ int4 stage[2048];     // 32 KB
  __shared__ float red[8];
  int t = threadIdx.x, lane = t & 63, w = t >> 6;
  int g = blockIdx.x;
  int b = g >> 9;                  // 512 blocks per batch
  int rbase = (g & 511) * 4;
  const float* sxp = ws + WS_SX + b * N_;
  const float* syp = ws + WS_SY + b * N_;
  const char* gbase = (const char*)(mask + (size_t)(b * N_ + rbase) * N_);
#pragma unroll
  for (int i = 0; i < 8; ++i) {
    int ci = i * 256 + w * 64;     // wave-slot chunk base
    __builtin_amdgcn_global_load_lds(
        (gas_ptr)(gbase + (size_t)(ci + lane) * 16),
        (las_ptr)&stage[ci], 16, 0, 0);
  }
  float4 xsA = *(const float4*)(sxp + t * 4);
  float4 ysA = *(const float4*)(syp + t * 4);
  float4 xsB = *(const float4*)(sxp + 1024 + t * 4);
  float4 ysB = *(const float4*)(syp + 1024 + t * 4);
  float rx[4], ry[4];
#pragma unroll
  for (int r = 0; r < 4; ++r) { rx[r] = sxp[rbase + r]; ry[r] = syp[rbase + r]; }
  asm volatile("s_waitcnt vmcnt(0)" ::: "memory");
  float acc = 0.0f;
  int cnt = 0;
#pragma unroll
  for (int i = 0; i < 8; ++i) {
    int4 m = stage[i * 256 + t];
    pair4(rx[i >> 1], ry[i >> 1], (i & 1) ? xsB : xsA, (i & 1) ? ysB : ysA,
          m, acc, cnt);
  }
  float cntf = (float)cnt;
#pragma unroll
  for (int off = 32; off > 0; off >>= 1) {
    acc += __shfl_xor(acc, off);
    cntf += __shfl_xor(cntf, off);
  }
  if (lane == 0) { red[w * 2] = acc; red[w * 2 + 1] = cntf; }
  __syncthreads();
  if (t == 0) {
    ws[WS_APART + g * 2 + 0] = red[0] + red[2] + red[4] + red[6];
    ws[WS_APART + g * 2 + 1] = red[1] + red[3] + red[5] + red[7];
  }
}

// Reduce 2048 anchor partials + combine with nll sum.
__global__ __launch_bounds__(256) void k_final(
    const float* __restrict__ ws, float* __restrict__ out) {
  __shared__ float red[8];
  int t = threadIdx.x, lane = t & 63, w = t >> 6;
  float a = 0.0f, c = 0.0f;
  for (int i = t; i < 2048; i += 256) {
    a += ws[WS_APART + i * 2 + 0];
    c += ws[WS_APART + i * 2 + 1];
  }
#pragma unroll
  for (int off = 32; off > 0; off >>= 1) {
    a += __shfl_xor(a, off);
    c += __shfl_xor(c, off);
  }
  if (lane == 0) { red[w * 2] = a; red[w * 2 + 1] = c; }
  __syncthreads();
  if (t == 0) {
    float at = red[0] + red[2] + red[4] + red[6];
    float ct = red[1] + red[3] + red[5] + red[7];
    out[0] = at / ct + 10.0f * ws[WS_NLL] * (1.0f / (float)BN_);
  }
}

extern "C" void kernel_launch(void* const* d_in, const int* in_sizes, int n_in,
                              void* d_out, int out_size, void* d_ws, size_t ws_size,
                              hipStream_t stream) {
  const float* emb    = (const float*)d_in[0];
  const float* contr  = (const float*)d_in[1];
  const float* absc   = (const float*)d_in[2];
  const int*   mask   = (const int*)d_in[3];
  const int*   labels = (const int*)d_in[4];
  float* ws  = (float*)d_ws;
  float* out = (float*)d_out;

  k_prep<<<2048, 256, 0, stream>>>(emb, absc, contr, ws);
  k_cluster<<<B_ * K_, 256, 0, stream>>>(contr, labels, ws);
  k_logits_nll<<<256, 128, 0, stream>>>(contr, labels, ws);
  k_anchor<<<2048, 256, 0, stream>>>(mask, ws);
  k_final<<<1, 256, 0, stream>>>(ws, out);
}